// Round 3
// baseline (344.381 us; speedup 1.0000x reference)
//
#include <hip/hip_runtime.h>

// GatedEncoderLayer: B=16, I=2048, J=1024, K=1024, F=32
// out[row,k] = sum_f [ (sum_j x[row,j]*Wy[j,f]) * Wx[row%I,f] ] * Wz[k,f]
constexpr int kI = 2048;
constexpr int kJ = 1024;
constexpr int kK = 1024;
constexpr int kF = 32;
constexpr int kRows = 16 * 2048;        // 32768

// ---------------------------------------------------------------------------
// Stage 1: t[row, f] = (sum_j x[row,j] * Wy[j,f]) * Wx[row%I, f]
// 1024 blocks x 256 threads; thread = (row-of-32, f-quad-of-8). acc = 4 regs.
// ---------------------------------------------------------------------------
__global__ __launch_bounds__(256, 4)
void ge_stage1(const float* __restrict__ x,
               const float* __restrict__ Wx,
               const float* __restrict__ Wy,
               float* __restrict__ t)
{
    const int tid  = threadIdx.x;
    const int rloc = tid >> 3;             // 0..31
    const int f0   = (tid & 7) * 4;        // 0,4,...,28
    const int row  = blockIdx.x * 32 + rloc;

    const float* __restrict__ xrow = x + (size_t)row * kJ;

    float4 acc = make_float4(0.f, 0.f, 0.f, 0.f);

#pragma unroll 2
    for (int j = 0; j < kJ; j += 8) {
        const float4 xv0 = *reinterpret_cast<const float4*>(xrow + j);
        const float4 xv1 = *reinterpret_cast<const float4*>(xrow + j + 4);
        const float xs[8] = {xv0.x, xv0.y, xv0.z, xv0.w,
                             xv1.x, xv1.y, xv1.z, xv1.w};
#pragma unroll
        for (int u = 0; u < 8; ++u) {
            const float4 w = *reinterpret_cast<const float4*>(
                Wy + (size_t)(j + u) * kF + f0);
            acc.x = fmaf(xs[u], w.x, acc.x);
            acc.y = fmaf(xs[u], w.y, acc.y);
            acc.z = fmaf(xs[u], w.z, acc.z);
            acc.w = fmaf(xs[u], w.w, acc.w);
        }
    }

    const int i = row & (kI - 1);
    const float4 g = *reinterpret_cast<const float4*>(Wx + (size_t)i * kF + f0);
    acc.x *= g.x; acc.y *= g.y; acc.z *= g.z; acc.w *= g.w;

    // threads 0..7 -> row0 f0..31 contiguous; wave = 1 KB contiguous store
    *reinterpret_cast<float4*>(t + (size_t)row * kF + f0) = acc;
}

// ---------------------------------------------------------------------------
// Stage 2: out[row, k] = sum_f t[row,f] * Wz[k,f]
// 2048 blocks x 256 threads; block = 16 rows, thread = 4 k-columns.
// Rows in 2 passes of 8 -> accumulator = 32 VGPR (no spill).
// ---------------------------------------------------------------------------
__global__ __launch_bounds__(256, 4)
void ge_stage2(const float* __restrict__ t,
               const float* __restrict__ Wz,
               float* __restrict__ out)
{
    __shared__ float t2[16][kF];           // 2 KB; reads are wave-uniform (broadcast)

    const int tid = threadIdx.x;
    const int rowBase = blockIdx.x * 16;

    if (tid < 128) {
        const int rr = tid >> 3, fq = tid & 7;
        *reinterpret_cast<float4*>(&t2[rr][fq * 4]) =
            *reinterpret_cast<const float4*>(t + (size_t)(rowBase + rr) * kF + fq * 4);
    }
    __syncthreads();

    const int k0 = tid * 4;                // 0..1020, lane-consecutive
    const size_t outBase = (size_t)rowBase * kK;

#pragma unroll
    for (int pass = 0; pass < 2; ++pass) {
        float4 acc[8];
#pragma unroll
        for (int r8 = 0; r8 < 8; ++r8) acc[r8] = make_float4(0.f, 0.f, 0.f, 0.f);

#pragma unroll
        for (int fq = 0; fq < 8; ++fq) {
            const float4 z0 = *reinterpret_cast<const float4*>(Wz + (size_t)(k0 + 0) * kF + fq * 4);
            const float4 z1 = *reinterpret_cast<const float4*>(Wz + (size_t)(k0 + 1) * kF + fq * 4);
            const float4 z2 = *reinterpret_cast<const float4*>(Wz + (size_t)(k0 + 2) * kF + fq * 4);
            const float4 z3 = *reinterpret_cast<const float4*>(Wz + (size_t)(k0 + 3) * kF + fq * 4);
#pragma unroll
            for (int r8 = 0; r8 < 8; ++r8) {
                const float4 tv = *reinterpret_cast<const float4*>(&t2[pass * 8 + r8][fq * 4]);
                acc[r8].x = fmaf(tv.x, z0.x, fmaf(tv.y, z0.y, fmaf(tv.z, z0.z, fmaf(tv.w, z0.w, acc[r8].x))));
                acc[r8].y = fmaf(tv.x, z1.x, fmaf(tv.y, z1.y, fmaf(tv.z, z1.z, fmaf(tv.w, z1.w, acc[r8].y))));
                acc[r8].z = fmaf(tv.x, z2.x, fmaf(tv.y, z2.y, fmaf(tv.z, z2.z, fmaf(tv.w, z2.w, acc[r8].z))));
                acc[r8].w = fmaf(tv.x, z3.x, fmaf(tv.y, z3.y, fmaf(tv.z, z3.z, fmaf(tv.w, z3.w, acc[r8].w))));
            }
        }

#pragma unroll
        for (int r8 = 0; r8 < 8; ++r8)
            *reinterpret_cast<float4*>(out + outBase + (size_t)(pass * 8 + r8) * kK + k0) = acc[r8];
    }
}

// ---------------------------------------------------------------------------
// Fallback: round-1 fused kernel (proven correct, 225 us) if ws too small.
// ---------------------------------------------------------------------------
__global__ __launch_bounds__(256, 2)
void gated_encoder_fused(const float* __restrict__ x,
                         const float* __restrict__ Wx,
                         const float* __restrict__ Wy,
                         const float* __restrict__ Wz,
                         float* __restrict__ out)
{
    __shared__ float t2[64][kF + 4];

    const int tid  = threadIdx.x;
    const int lane = tid & 63;
    const int wv   = tid >> 6;

    const int rloc = wv * 16 + (lane >> 2);
    const int row  = blockIdx.x * 64 + rloc;
    const int fg8  = (lane & 3) * 8;

    const float* __restrict__ xrow = x + (size_t)row * kJ;

    float acc[8];
#pragma unroll
    for (int u = 0; u < 8; ++u) acc[u] = 0.0f;

    for (int j = 0; j < kJ; j += 8) {
        const float4 xv0 = *reinterpret_cast<const float4*>(xrow + j);
        const float4 xv1 = *reinterpret_cast<const float4*>(xrow + j + 4);
        const float xs[8] = {xv0.x, xv0.y, xv0.z, xv0.w,
                             xv1.x, xv1.y, xv1.z, xv1.w};
#pragma unroll
        for (int u = 0; u < 8; ++u) {
            const float* wyp = Wy + (size_t)(j + u) * kF + fg8;
            const float4 w0 = *reinterpret_cast<const float4*>(wyp);
            const float4 w1 = *reinterpret_cast<const float4*>(wyp + 4);
            acc[0] = fmaf(xs[u], w0.x, acc[0]);
            acc[1] = fmaf(xs[u], w0.y, acc[1]);
            acc[2] = fmaf(xs[u], w0.z, acc[2]);
            acc[3] = fmaf(xs[u], w0.w, acc[3]);
            acc[4] = fmaf(xs[u], w1.x, acc[4]);
            acc[5] = fmaf(xs[u], w1.y, acc[5]);
            acc[6] = fmaf(xs[u], w1.z, acc[6]);
            acc[7] = fmaf(xs[u], w1.w, acc[7]);
        }
    }

    const int i = row & (kI - 1);
    const float* wxp = Wx + (size_t)i * kF + fg8;
    const float4 g0 = *reinterpret_cast<const float4*>(wxp);
    const float4 g1 = *reinterpret_cast<const float4*>(wxp + 4);
    float4 r0, r1;
    r0.x = acc[0] * g0.x;  r0.y = acc[1] * g0.y;
    r0.z = acc[2] * g0.z;  r0.w = acc[3] * g0.w;
    r1.x = acc[4] * g1.x;  r1.y = acc[5] * g1.y;
    r1.z = acc[6] * g1.z;  r1.w = acc[7] * g1.w;
    *reinterpret_cast<float4*>(&t2[rloc][fg8])     = r0;
    *reinterpret_cast<float4*>(&t2[rloc][fg8 + 4]) = r1;

    __syncthreads();

    const size_t outBase = (size_t)blockIdx.x * 64 * kK;

#pragma unroll
    for (int pass = 0; pass < 2; ++pass) {
        const int k1 = pass * 512 + tid;
        const int k2 = k1 + 256;
        const float* wz1 = Wz + (size_t)k1 * kF;
        const float* wz2 = Wz + (size_t)k2 * kF;
        float4 z1[8], z2[8];
#pragma unroll
        for (int m = 0; m < 8; ++m) {
            z1[m] = *reinterpret_cast<const float4*>(wz1 + 4 * m);
            z2[m] = *reinterpret_cast<const float4*>(wz2 + 4 * m);
        }
        for (int r = 0; r < 64; ++r) {
            float4 a1 = {0.f, 0.f, 0.f, 0.f};
            float4 a2 = {0.f, 0.f, 0.f, 0.f};
#pragma unroll
            for (int m = 0; m < 8; ++m) {
                const float4 tv = *reinterpret_cast<const float4*>(&t2[r][4 * m]);
                a1.x = fmaf(tv.x, z1[m].x, a1.x);
                a1.y = fmaf(tv.y, z1[m].y, a1.y);
                a1.z = fmaf(tv.z, z1[m].z, a1.z);
                a1.w = fmaf(tv.w, z1[m].w, a1.w);
                a2.x = fmaf(tv.x, z2[m].x, a2.x);
                a2.y = fmaf(tv.y, z2[m].y, a2.y);
                a2.z = fmaf(tv.z, z2[m].z, a2.z);
                a2.w = fmaf(tv.w, z2[m].w, a2.w);
            }
            out[outBase + (size_t)r * kK + k1] = (a1.x + a1.y) + (a1.z + a1.w);
            out[outBase + (size_t)r * kK + k2] = (a2.x + a2.y) + (a2.z + a2.w);
        }
    }
}

extern "C" void kernel_launch(void* const* d_in, const int* in_sizes, int n_in,
                              void* d_out, int out_size, void* d_ws, size_t ws_size,
                              hipStream_t stream) {
    const float* x  = (const float*)d_in[0];   // (B, I, J)
    const float* Wx = (const float*)d_in[1];   // (I, F)
    const float* Wy = (const float*)d_in[2];   // (J, F)
    const float* Wz = (const float*)d_in[3];   // (K, F)
    float* out = (float*)d_out;                // (B, I, K) f32

    const size_t tBytes = (size_t)kRows * kF * sizeof(float);   // 4 MiB

    if (ws_size >= tBytes && d_ws != nullptr) {
        float* t = (float*)d_ws;
        ge_stage1<<<dim3(kRows / 32), 256, 0, stream>>>(x, Wx, Wy, t);
        ge_stage2<<<dim3(kRows / 16), 256, 0, stream>>>(t, Wz, out);
    } else {
        gated_encoder_fused<<<dim3(kRows / 64), 256, 0, stream>>>(x, Wx, Wy, Wz, out);
    }
}